// Round 4
// baseline (1320.480 us; speedup 1.0000x reference)
//
#include <hip/hip_runtime.h>

// R=2048, S=64, V=8. T=4 (r,s) points per 256-thread block.
// Per-view MLP phases: v = tid>>5 (view 0..7), l = tid&31 (neuron lane).
// Activation LDS layout is [view][feat][T] so the 4 per-point values are one
// 16B float4 -> ds_read_b128/ds_write_b128, cutting LDS instruction count 4x.
// Weights stream from global (L1/L2-cached, shared by all blocks); each weight
// fetched by a wave feeds 4-8 FMAs.

#define NRS (2048*64)
#define T 4

__device__ __forceinline__ float eluf(float x){ return x > 0.f ? x : __expf(x)-1.f; }
__device__ __forceinline__ float sigmf(float x){ return 1.f/(1.f+__expf(-x)); }
__device__ __forceinline__ float4 elu4(float4 a){
    return make_float4(eluf(a.x), eluf(a.y), eluf(a.z), eluf(a.w));
}

#define FMA4(A, X, W) do { \
    A.x = fmaf((X).x, (W), A.x); \
    A.y = fmaf((X).y, (W), A.y); \
    A.z = fmaf((X).z, (W), A.z); \
    A.w = fmaf((X).w, (W), A.w); } while(0)

__global__ __launch_bounds__(256, 4) void nerf_fused(
    const float* __restrict__ g_rgb,  const float* __restrict__ g_nr,
    const float* __restrict__ g_rd,   const float* __restrict__ g_mask,
    const float* __restrict__ rd_w1,  const float* __restrict__ rd_b1,
    const float* __restrict__ rd_w2,  const float* __restrict__ rd_b2,
    const float* __restrict__ rf_w1,  const float* __restrict__ rf_b1,
    const float* __restrict__ rf_w2,  const float* __restrict__ rf_b2,
    const float* __restrict__ nr_w1,  const float* __restrict__ nr_b1,
    const float* __restrict__ nr_w2,  const float* __restrict__ nr_b2,
    const float* __restrict__ base_w1,const float* __restrict__ base_b1,
    const float* __restrict__ base_w2,const float* __restrict__ base_b2,
    const float* __restrict__ vis_w1, const float* __restrict__ vis_b1,
    const float* __restrict__ vis_w2, const float* __restrict__ vis_b2,
    const float* __restrict__ v2_w1,  const float* __restrict__ v2_b1,
    const float* __restrict__ v2_w2,  const float* __restrict__ v2_b2,
    float* __restrict__ out)
{
    // [view][feat][T] activation tiles (inner [T]=16B, float4-accessed)
    __shared__ __align__(16) float s_rgb [8][35][T]; // rgb_feat; becomes rgb_feat_ in-place at P2
    __shared__ __align__(16) float s_nr  [8][32][T];
    __shared__ __align__(16) float s_rd  [8][4][T];
    __shared__ __align__(16) float s_h16 [8][16][T]; // rd hidden
    __shared__ __align__(16) float s_h8  [8][8][T];  // nr hidden
    __shared__ __align__(16) float s_hid [8][64][T]; // generic hidden (rf/base/vis/v2 l1)
    __shared__ __align__(16) float s_f1  [8][64][T]; // rf layer2 (pre-max)
    __shared__ __align__(16) float s_x   [8][32][T]; // base output / residual x
    __shared__ float s_gmax[T][64];
    __shared__ float s_global[T][140];  // [mean0|var0|mean1|var1]
    __shared__ float s_gc  [T][64];     // globalfeat part of base layer1
    __shared__ float s_mask[T][8];
    __shared__ float s_w0  [T][8];
    __shared__ float s_wt  [T][8];
    __shared__ float s_vis [T][8];

    const int rs0 = blockIdx.x * T;
    const int tid = threadIdx.x;
    const int v   = tid >> 5;
    const int l   = tid & 31;

    // ---- P0: staging (coalesced global reads, transposed LDS writes) ----
    {
        const float* src = g_rgb + (size_t)rs0 * 280;           // [t][v][f], f=35
        for (int idx = tid; idx < 1120; idx += 256) {
            const int t = idx / 280;
            const int r = idx - t * 280;
            const int vv = r / 35;
            const int f  = r - vv * 35;
            s_rgb[vv][f][t] = src[idx];
        }
        const float* srcn = g_nr + (size_t)rs0 * 256;           // [t][v][f], f=32
        for (int idx = tid; idx < 1024; idx += 256)
            s_nr[(idx >> 5) & 7][idx & 31][idx >> 8] = srcn[idx];
        if (tid < 128)                                          // [t][v][f], f=4
            s_rd[(tid >> 2) & 7][tid & 3][tid >> 5] = g_rd[(size_t)rs0 * 32 + tid];
        if (tid < 32)
            s_mask[tid >> 3][tid & 7] = g_mask[(size_t)rs0 * 8 + tid];
    }
    __syncthreads();

    // ---- P1: rf layer1 (relu, all lanes); rd layer1 (l<16); nr layer1 (16<=l<24) ----
    {
        const float b0 = rf_b1[l], b1 = rf_b1[l + 32];
        float4 a0 = make_float4(b0, b0, b0, b0);
        float4 a1 = make_float4(b1, b1, b1, b1);
        #pragma unroll
        for (int i = 0; i < 35; ++i) {
            const float4 xv = *reinterpret_cast<const float4*>(s_rgb[v][i]);
            const float w0 = rf_w1[i*64 + l];
            const float w1 = rf_w1[i*64 + l + 32];
            FMA4(a0, xv, w0);
            FMA4(a1, xv, w1);
        }
        *reinterpret_cast<float4*>(s_hid[v][l]) =
            make_float4(fmaxf(a0.x,0.f), fmaxf(a0.y,0.f), fmaxf(a0.z,0.f), fmaxf(a0.w,0.f));
        *reinterpret_cast<float4*>(s_hid[v][l+32]) =
            make_float4(fmaxf(a1.x,0.f), fmaxf(a1.y,0.f), fmaxf(a1.z,0.f), fmaxf(a1.w,0.f));

        if (l < 16) {
            const float bb = rd_b1[l];
            float4 acc = make_float4(bb, bb, bb, bb);
            #pragma unroll
            for (int i = 0; i < 4; ++i) {
                const float4 xv = *reinterpret_cast<const float4*>(s_rd[v][i]);
                FMA4(acc, xv, rd_w1[i*16 + l]);
            }
            *reinterpret_cast<float4*>(s_h16[v][l]) = elu4(acc);
        } else if (l < 24) {
            const int o = l - 16;
            const float bb = nr_b1[o];
            float4 acc = make_float4(bb, bb, bb, bb);
            #pragma unroll
            for (int i = 0; i < 32; ++i) {
                const float4 xv = *reinterpret_cast<const float4*>(s_nr[v][i]);
                FMA4(acc, xv, nr_w1[i*8 + o]);
            }
            *reinterpret_cast<float4*>(s_h8[v][o]) = elu4(acc);
        }
    }
    __syncthreads();

    // ---- P2: rd l2 -> rgb_feat_ (in-place); rf l2 -> f1; weight0; weight ----
    {
        for (int o = l; o < 35; o += 32) {
            const float bb = rd_b2[o];
            float4 acc = make_float4(bb, bb, bb, bb);
            #pragma unroll
            for (int i = 0; i < 16; ++i) {
                const float4 h = *reinterpret_cast<const float4*>(s_h16[v][i]);
                FMA4(acc, h, rd_w2[i*35 + o]);
            }
            float4 r = *reinterpret_cast<const float4*>(s_rgb[v][o]);
            r.x += eluf(acc.x); r.y += eluf(acc.y); r.z += eluf(acc.z); r.w += eluf(acc.w);
            *reinterpret_cast<float4*>(s_rgb[v][o]) = r;   // s_rgb is now rgb_feat_
        }

        const float b0 = rf_b2[l], b1 = rf_b2[l + 32];
        float4 a0 = make_float4(b0, b0, b0, b0);
        float4 a1 = make_float4(b1, b1, b1, b1);
        #pragma unroll
        for (int i = 0; i < 64; ++i) {
            const float4 h = *reinterpret_cast<const float4*>(s_hid[v][i]);
            FMA4(a0, h, rf_w2[i*64 + l]);
            FMA4(a1, h, rf_w2[i*64 + l + 32]);
        }
        *reinterpret_cast<float4*>(s_f1[v][l])    = a0;
        *reinterpret_cast<float4*>(s_f1[v][l+32]) = a1;

        if (tid < 32) {                       // weight0 = sigmoid(nr l2)
            const int tt = tid >> 3, vv = tid & 7;
            float acc = nr_b2[0];
            #pragma unroll
            for (int i = 0; i < 8; ++i) acc = fmaf(s_h8[vv][i][tt], nr_w2[i], acc);
            s_w0[tt][vv] = sigmf(acc);
        } else if (tid < 64) {                // weight = mask / (sum+eps)
            const int tt = (tid - 32) >> 3, vv = tid & 7;
            float ms = 0.f;
            #pragma unroll
            for (int i = 0; i < 8; ++i) ms += s_mask[tt][i];
            s_wt[tt][vv] = s_mask[tt][vv] / (ms + 1e-8f);
        }
    }
    __syncthreads();

    // ---- P3: gmax (one (t,o) per thread) + fmv -> s_global (tid<140) ----
    {
        const int tg = tid >> 6, og = tid & 63;
        float m = s_f1[0][og][tg];
        #pragma unroll
        for (int vv = 1; vv < 8; ++vv) m = fmaxf(m, s_f1[vv][og][tg]);
        s_gmax[tg][og] = m;

        if (tid < 140) {
            const int tt = tid / 35, f = tid - tt * 35;
            float m0 = 0.f, m1 = 0.f;
            #pragma unroll
            for (int vv = 0; vv < 8; ++vv) {
                const float p = s_rgb[vv][f][tt];
                m0 = fmaf(p, s_w0[tt][vv], m0);
                m1 = fmaf(p, s_wt[tt][vv], m1);
            }
            float v0 = 0.f, v1 = 0.f;
            #pragma unroll
            for (int vv = 0; vv < 8; ++vv) {
                const float p = s_rgb[vv][f][tt];
                const float d0 = p - m0, d1 = p - m1;
                v0 = fmaf(s_w0[tt][vv] * d0, d0, v0);
                v1 = fmaf(s_wt[tt][vv] * d1, d1, v1);
            }
            s_global[tt][f]       = m0;
            s_global[tt][35 + f]  = v0;
            s_global[tt][70 + f]  = m1;
            s_global[tt][105 + f] = v1;
        }
    }
    __syncthreads();

    // ---- P4: base layer1. Global 140-part once per (t,o); per-view part per (v,l). ----
    float4 pa0 = make_float4(0.f, 0.f, 0.f, 0.f);
    float4 pa1 = make_float4(0.f, 0.f, 0.f, 0.f);
    {
        const int tg = tid >> 6, og = tid & 63;
        float acc = 0.f;
        #pragma unroll 10
        for (int i = 0; i < 140; ++i) acc = fmaf(s_global[tg][i], base_w1[i*64 + og], acc);
        s_gc[tg][og] = acc;

        #pragma unroll
        for (int i = 0; i < 35; ++i) {
            const float4 xv = *reinterpret_cast<const float4*>(s_rgb[v][i]);
            FMA4(pa0, xv, base_w1[(140+i)*64 + l]);
            FMA4(pa1, xv, base_w1[(140+i)*64 + l + 32]);
        }
        #pragma unroll
        for (int i = 0; i < 32; ++i) {
            const float4 xv = *reinterpret_cast<const float4*>(s_nr[v][i]);
            FMA4(pa0, xv, base_w1[(175+i)*64 + l]);
            FMA4(pa1, xv, base_w1[(175+i)*64 + l + 32]);
        }
    }
    __syncthreads();

    // ---- P5: combine + elu -> hid ----
    {
        const float b0 = base_b1[l], b1 = base_b1[l + 32];
        float4 h0, h1;
        h0.x = eluf(pa0.x + s_gc[0][l] + b0);
        h0.y = eluf(pa0.y + s_gc[1][l] + b0);
        h0.z = eluf(pa0.z + s_gc[2][l] + b0);
        h0.w = eluf(pa0.w + s_gc[3][l] + b0);
        h1.x = eluf(pa1.x + s_gc[0][l+32] + b1);
        h1.y = eluf(pa1.y + s_gc[1][l+32] + b1);
        h1.z = eluf(pa1.z + s_gc[2][l+32] + b1);
        h1.w = eluf(pa1.w + s_gc[3][l+32] + b1);
        *reinterpret_cast<float4*>(s_hid[v][l])    = h0;
        *reinterpret_cast<float4*>(s_hid[v][l+32]) = h1;
    }
    __syncthreads();

    // ---- P6: base layer2 -> x ----
    {
        const float bb = base_b2[l];
        float4 acc = make_float4(bb, bb, bb, bb);
        #pragma unroll
        for (int i = 0; i < 64; ++i) {
            const float4 h = *reinterpret_cast<const float4*>(s_hid[v][i]);
            FMA4(acc, h, base_w2[i*32 + l]);
        }
        *reinterpret_cast<float4*>(s_x[v][l]) = elu4(acc);
    }
    __syncthreads();

    // ---- P7: vis layer1 (input x*weight; scalar hoisted) ----
    {
        float4 acc = make_float4(0.f, 0.f, 0.f, 0.f);
        #pragma unroll
        for (int i = 0; i < 32; ++i) {
            const float4 x = *reinterpret_cast<const float4*>(s_x[v][i]);
            FMA4(acc, x, vis_w1[i*32 + l]);
        }
        const float bb = vis_b1[l];
        float4 h;
        h.x = eluf(acc.x * s_wt[0][v] + bb);
        h.y = eluf(acc.y * s_wt[1][v] + bb);
        h.z = eluf(acc.z * s_wt[2][v] + bb);
        h.w = eluf(acc.w * s_wt[3][v] + bb);
        *reinterpret_cast<float4*>(s_hid[v][l]) = h;
    }
    __syncthreads();

    // ---- P8: vis layer2: x += x_res; vis channel (out 32) on tid<32 ----
    {
        const float bb = vis_b2[l];
        float4 acc = make_float4(bb, bb, bb, bb);
        #pragma unroll
        for (int i = 0; i < 32; ++i) {
            const float4 h = *reinterpret_cast<const float4*>(s_hid[v][i]);
            FMA4(acc, h, vis_w2[i*33 + l]);
        }
        float4 x = *reinterpret_cast<const float4*>(s_x[v][l]);
        x.x += eluf(acc.x); x.y += eluf(acc.y); x.z += eluf(acc.z); x.w += eluf(acc.w);
        *reinterpret_cast<float4*>(s_x[v][l]) = x;

        if (tid < 32) {
            const int tt = tid >> 3, vv = tid & 7;
            float a2 = vis_b2[32];
            #pragma unroll
            for (int i = 0; i < 32; ++i) a2 = fmaf(s_hid[vv][i][tt], vis_w2[i*33 + 32], a2);
            s_vis[tt][vv] = sigmf(eluf(a2)) * s_mask[tt][vv];
        }
    }
    __syncthreads();

    // ---- P9: v2 layer1 (input x*vis; scalar hoisted) ----
    {
        float4 acc = make_float4(0.f, 0.f, 0.f, 0.f);
        #pragma unroll
        for (int i = 0; i < 32; ++i) {
            const float4 x = *reinterpret_cast<const float4*>(s_x[v][i]);
            FMA4(acc, x, v2_w1[i*32 + l]);
        }
        const float bb = v2_b1[l];
        float4 h;
        h.x = eluf(acc.x * s_vis[0][v] + bb);
        h.y = eluf(acc.y * s_vis[1][v] + bb);
        h.z = eluf(acc.z * s_vis[2][v] + bb);
        h.w = eluf(acc.w * s_vis[3][v] + bb);
        *reinterpret_cast<float4*>(s_hid[v][l]) = h;
    }
    __syncthreads();

    // ---- P10: v2 layer2 (1 out per (t,view)) -> final vis ----
    if (tid < 32) {
        const int tt = tid >> 3, vv = tid & 7;
        float acc = v2_b2[0];
        #pragma unroll
        for (int i = 0; i < 32; ++i) acc = fmaf(s_hid[vv][i][tt], v2_w2[i], acc);
        s_vis[tt][vv] = sigmf(acc) * s_mask[tt][vv];
    }
    __syncthreads();

    // ---- P12: final fmv + gmax, write out. One (t,col) per thread (tid<128). ----
    if (tid < 128) {
        const int tt = tid >> 5, col = tid & 31;
        float vs = 0.f;
        #pragma unroll
        for (int vv = 0; vv < 8; ++vv) vs += s_vis[tt][vv];
        const float inv = 1.f / (vs + 1e-8f);
        float mean = 0.f;
        #pragma unroll
        for (int vv = 0; vv < 8; ++vv) mean = fmaf(s_x[vv][col][tt], s_vis[tt][vv], mean);
        mean *= inv;
        float var = 0.f;
        #pragma unroll
        for (int vv = 0; vv < 8; ++vv) {
            const float d = s_x[vv][col][tt] - mean;
            var = fmaf(s_vis[tt][vv] * d, d, var);
        }
        var *= inv;
        const size_t ob = ((size_t)rs0 + tt) * 64;
        out[ob + col]      = mean + s_gmax[tt][col];
        out[ob + 32 + col] = var  + s_gmax[tt][32 + col];
    }
}

extern "C" void kernel_launch(void* const* d_in, const int* in_sizes, int n_in,
                              void* d_out, int out_size, void* d_ws, size_t ws_size,
                              hipStream_t stream) {
    const float* g_rgb   = (const float*)d_in[0];
    const float* g_nr    = (const float*)d_in[1];
    const float* g_rd    = (const float*)d_in[2];
    const float* g_mask  = (const float*)d_in[3];
    // d_in[4] que_pts, d_in[5] que_dir: unused by the reference
    const float* rd_w1   = (const float*)d_in[6];
    const float* rd_b1   = (const float*)d_in[7];
    const float* rd_w2   = (const float*)d_in[8];
    const float* rd_b2   = (const float*)d_in[9];
    const float* rf_w1   = (const float*)d_in[10];
    const float* rf_b1   = (const float*)d_in[11];
    const float* rf_w2   = (const float*)d_in[12];
    const float* rf_b2   = (const float*)d_in[13];
    const float* nr_w1   = (const float*)d_in[14];
    const float* nr_b1   = (const float*)d_in[15];
    const float* nr_w2   = (const float*)d_in[16];
    const float* nr_b2   = (const float*)d_in[17];
    const float* base_w1 = (const float*)d_in[18];
    const float* base_b1 = (const float*)d_in[19];
    const float* base_w2 = (const float*)d_in[20];
    const float* base_b2 = (const float*)d_in[21];
    const float* vis_w1  = (const float*)d_in[22];
    const float* vis_b1  = (const float*)d_in[23];
    const float* vis_w2  = (const float*)d_in[24];
    const float* vis_b2  = (const float*)d_in[25];
    const float* v2_w1   = (const float*)d_in[26];
    const float* v2_b1   = (const float*)d_in[27];
    const float* v2_w2   = (const float*)d_in[28];
    const float* v2_b2   = (const float*)d_in[29];
    float* out = (float*)d_out;

    hipLaunchKernelGGL(nerf_fused, dim3(NRS / T), dim3(256), 0, stream,
        g_rgb, g_nr, g_rd, g_mask,
        rd_w1, rd_b1, rd_w2, rd_b2,
        rf_w1, rf_b1, rf_w2, rf_b2,
        nr_w1, nr_b1, nr_w2, nr_b2,
        base_w1, base_b1, base_w2, base_b2,
        vis_w1, vis_b1, vis_w2, vis_b2,
        v2_w1, v2_b1, v2_w2, v2_b2,
        out);
}

// Round 6
// 1305.159 us; speedup vs baseline: 1.0117x; 1.0117x over previous
//
#include <hip/hip_runtime.h>

// R=2048, S=64, V=8. One 64-lane wave per block = 8 points (t) x 8 views (v),
// lane = t*8+v. ALL activations live in registers (k-outer loops, static acc
// arrays); weights stream as wave-uniform s_loads in natural [k][o] row-major
// order (rows contiguous). Cross-view reductions via __shfl_xor over the 8
// view-lanes. LDS only for 4 small cross-lane handoffs (barriered).

#define NRS (2048*64)

__device__ __forceinline__ float eluf(float x){ return x > 0.f ? x : __expf(x)-1.f; }
__device__ __forceinline__ float sigmf(float x){ return 1.f/(1.f+__expf(-x)); }
__device__ __forceinline__ float sum8(float x){
    x += __shfl_xor(x, 1); x += __shfl_xor(x, 2); x += __shfl_xor(x, 4); return x;
}
__device__ __forceinline__ float max8(float x){
    x = fmaxf(x, __shfl_xor(x, 1)); x = fmaxf(x, __shfl_xor(x, 2)); x = fmaxf(x, __shfl_xor(x, 4)); return x;
}

__global__ __launch_bounds__(64, 2) void nerf_main(
    const float* __restrict__ g_rgb,  const float* __restrict__ g_nr,
    const float* __restrict__ g_rd,   const float* __restrict__ g_mask,
    const float* __restrict__ rd_w1,  const float* __restrict__ rd_b1,
    const float* __restrict__ rd_w2,  const float* __restrict__ rd_b2,
    const float* __restrict__ rf_w1,  const float* __restrict__ rf_b1,
    const float* __restrict__ rf_w2,  const float* __restrict__ rf_b2,
    const float* __restrict__ nr_w1,  const float* __restrict__ nr_b1,
    const float* __restrict__ nr_w2,  const float* __restrict__ nr_b2,
    const float* __restrict__ base_w1,const float* __restrict__ base_b1,
    const float* __restrict__ base_w2,const float* __restrict__ base_b2,
    const float* __restrict__ vis_w1, const float* __restrict__ vis_b1,
    const float* __restrict__ vis_w2, const float* __restrict__ vis_b2,
    const float* __restrict__ v2_w1,  const float* __restrict__ v2_b1,
    const float* __restrict__ v2_w2,  const float* __restrict__ v2_b2,
    float* __restrict__ out)
{
    __shared__ __align__(16) float g_lds[8*144];   // globalfeat [t][140] (pad 144)
    __shared__ float gc_lds  [8*65];               // base-l1 globalfeat partial [t][o]
    __shared__ float gmax_lds[8*65];               // rgb_feat_max [t][o]
    __shared__ float out_lds [512];

    const int lane = threadIdx.x;      // 0..63
    const int t    = lane >> 3;        // point within block
    const int v    = lane & 7;         // view
    const int pid  = blockIdx.x * 64 + lane;   // global (point*8 + view)

    // ---- inputs (per-lane gathers; region per wave is contiguous -> L1 reuse) ----
    float rgb[35];
    #pragma unroll
    for (int k = 0; k < 35; ++k) rgb[k] = g_rgb[(size_t)pid*35 + k];
    float rdv[4];
    #pragma unroll
    for (int k = 0; k < 4; ++k) rdv[k] = g_rd[(size_t)pid*4 + k];
    float nrv[32];
    #pragma unroll
    for (int k = 0; k < 32; ++k) nrv[k] = g_nr[(size_t)pid*32 + k];
    const float mask = g_mask[pid];
    const float wt   = mask / (sum8(mask) + 1e-8f);

    // ---- rf layer1 (k-outer, acc in regs, natural [k][64] weight rows) ----
    float x64[64];
    {
        float acc[64];
        #pragma unroll
        for (int o = 0; o < 64; ++o) acc[o] = rf_b1[o];
        #pragma unroll 1
        for (int k = 0; k < 35; ++k) {
            const float xk = rgb[k];
            #pragma unroll
            for (int o = 0; o < 64; ++o) acc[o] = fmaf(xk, rf_w1[k*64 + o], acc[o]);
        }
        #pragma unroll
        for (int o = 0; o < 64; ++o) x64[o] = fmaxf(acc[o], 0.f);
    }

    // ---- rd MLP: rgb -> rgb_feat_ in place (frees rdv early) ----
    {
        float h16[16];
        #pragma unroll
        for (int o = 0; o < 16; ++o) {
            float a = rd_b1[o];
            #pragma unroll
            for (int k = 0; k < 4; ++k) a = fmaf(rdv[k], rd_w1[k*16 + o], a);
            h16[o] = eluf(a);
        }
        #pragma unroll 1
        for (int o = 0; o < 35; ++o) {
            float a = rd_b2[o];
            #pragma unroll
            for (int k = 0; k < 16; ++k) a = fmaf(h16[k], rd_w2[k*35 + o], a);
            rgb[o] += eluf(a);             // rgb is now rgb_feat_
        }
    }

    // ---- rf layer2 -> gmax (only consumer is max over views) ----
    {
        float acc[64];
        #pragma unroll
        for (int o = 0; o < 64; ++o) acc[o] = rf_b2[o];
        #pragma unroll 1
        for (int k = 0; k < 64; ++k) {
            const float xk = x64[k];
            #pragma unroll
            for (int o = 0; o < 64; ++o) acc[o] = fmaf(xk, rf_w2[k*64 + o], acc[o]);
        }
        #pragma unroll
        for (int o = 0; o < 64; ++o) {
            const float gm = max8(acc[o]);
            if (v == (o & 7)) gmax_lds[t*65 + o] = gm;
        }
    }

    // ---- nr MLP -> weight0 ----
    float w0;
    {
        float h8[8];
        #pragma unroll
        for (int o = 0; o < 8; ++o) h8[o] = nr_b1[o];
        #pragma unroll 4
        for (int k = 0; k < 32; ++k) {
            const float xk = nrv[k];
            #pragma unroll
            for (int o = 0; o < 8; ++o) h8[o] = fmaf(xk, nr_w1[k*8 + o], h8[o]);
        }
        float a = nr_b2[0];
        #pragma unroll
        for (int k = 0; k < 8; ++k) a = fmaf(eluf(h8[k]), nr_w2[k], a);
        w0 = sigmf(a);
    }

    // ---- fmv (two-pass, matches reference exactly) -> g_lds[t][140] ----
    #pragma unroll 2
    for (int f = 0; f < 35; ++f) {
        const float a  = rgb[f];
        const float m0 = sum8(w0 * a);
        const float d0 = a - m0;
        const float v0 = sum8(w0 * d0 * d0);
        const float m1 = sum8(wt * a);
        const float d1 = a - m1;
        const float v1 = sum8(wt * d1 * d1);
        if (v == (f & 7)) {
            g_lds[t*144 + f]       = m0;
            g_lds[t*144 + 35 + f]  = v0;
            g_lds[t*144 + 70 + f]  = m1;
            g_lds[t*144 + 105 + f] = v1;
        }
    }
    __syncthreads();

    // ---- globalfeat part of base-l1: lane = o; g broadcast, coalesced w ----
    {
        float ga[8];
        #pragma unroll
        for (int q = 0; q < 8; ++q) ga[q] = 0.f;
        #pragma unroll 1
        for (int i = 0; i < 140; i += 4) {
            float w_[4];
            #pragma unroll
            for (int j = 0; j < 4; ++j) w_[j] = base_w1[(i + j)*64 + lane];
            #pragma unroll
            for (int q = 0; q < 8; ++q) {
                const float4 gv = *reinterpret_cast<const float4*>(&g_lds[q*144 + i]);
                ga[q] = fmaf(gv.x, w_[0], ga[q]);
                ga[q] = fmaf(gv.y, w_[1], ga[q]);
                ga[q] = fmaf(gv.z, w_[2], ga[q]);
                ga[q] = fmaf(gv.w, w_[3], ga[q]);
            }
        }
        #pragma unroll
        for (int q = 0; q < 8; ++q) gc_lds[q*65 + lane] = ga[q];
    }
    __syncthreads();

    // ---- base layer1 (view part, k-outer; natural [140+k][64] rows) ----
    {
        float acc[64];
        #pragma unroll
        for (int o = 0; o < 64; ++o) acc[o] = base_b1[o] + gc_lds[t*65 + o];
        #pragma unroll 1
        for (int k = 0; k < 35; ++k) {
            const float xk = rgb[k];
            #pragma unroll
            for (int o = 0; o < 64; ++o) acc[o] = fmaf(xk, base_w1[(140+k)*64 + o], acc[o]);
        }
        #pragma unroll 1
        for (int k = 0; k < 32; ++k) {
            const float xk = nrv[k];
            #pragma unroll
            for (int o = 0; o < 64; ++o) acc[o] = fmaf(xk, base_w1[(175+k)*64 + o], acc[o]);
        }
        #pragma unroll
        for (int o = 0; o < 64; ++o) x64[o] = eluf(acc[o]);
    }

    // ---- base layer2 -> x2 (k-outer, natural [k][32] rows) ----
    float x2[32];
    {
        #pragma unroll
        for (int o = 0; o < 32; ++o) x2[o] = base_b2[o];
        #pragma unroll 2
        for (int k = 0; k < 64; ++k) {
            const float xk = x64[k];
            #pragma unroll
            for (int o = 0; o < 32; ++o) x2[o] = fmaf(xk, base_w2[k*32 + o], x2[o]);
        }
        #pragma unroll
        for (int o = 0; o < 32; ++o) x2[o] = eluf(x2[o]);
    }

    // ---- vis MLP (input x*wt; scalar hoisted) ----
    float hv[32];
    {
        float acc[32];
        #pragma unroll
        for (int o = 0; o < 32; ++o) acc[o] = 0.f;
        #pragma unroll 2
        for (int k = 0; k < 32; ++k) {
            const float xk = x2[k];
            #pragma unroll
            for (int o = 0; o < 32; ++o) acc[o] = fmaf(xk, vis_w1[k*32 + o], acc[o]);
        }
        #pragma unroll
        for (int o = 0; o < 32; ++o) hv[o] = eluf(fmaf(acc[o], wt, vis_b1[o]));
    }
    float vis1;
    {
        float acc[32];
        #pragma unroll
        for (int o = 0; o < 32; ++o) acc[o] = vis_b2[o];
        float a2 = vis_b2[32];
        #pragma unroll 2
        for (int k = 0; k < 32; ++k) {
            const float hk = hv[k];
            #pragma unroll
            for (int o = 0; o < 32; ++o) acc[o] = fmaf(hk, vis_w2[k*33 + o], acc[o]);
            a2 = fmaf(hk, vis_w2[k*33 + 32], a2);
        }
        #pragma unroll
        for (int o = 0; o < 32; ++o) x2[o] += eluf(acc[o]);   // x = x + x_res
        vis1 = sigmf(eluf(a2)) * mask;
    }

    // ---- v2 MLP (input x*vis1; scalar hoisted) -> final vis ----
    float vis2;
    {
        float acc[32];
        #pragma unroll
        for (int o = 0; o < 32; ++o) acc[o] = 0.f;
        #pragma unroll 2
        for (int k = 0; k < 32; ++k) {
            const float xk = x2[k];
            #pragma unroll
            for (int o = 0; o < 32; ++o) acc[o] = fmaf(xk, v2_w1[k*32 + o], acc[o]);
        }
        float a = v2_b2[0];
        #pragma unroll
        for (int k = 0; k < 32; ++k) a = fmaf(eluf(fmaf(acc[k], vis1, v2_b1[k])), v2_w2[k], a);
        vis2 = sigmf(a) * mask;
    }

    // ---- final fmv (weight2 = vis2 normalized; two-pass) + gmax ----
    {
        const float w2 = vis2 / (sum8(vis2) + 1e-8f);
        #pragma unroll 2
        for (int c = 0; c < 32; ++c) {
            const float xv = x2[c];
            const float m  = sum8(w2 * xv);
            const float d  = xv - m;
            const float va = sum8(w2 * d * d);
            if (v == (c & 7)) {
                out_lds[t*64 + c]      = m  + gmax_lds[t*65 + c];
                out_lds[t*64 + 32 + c] = va + gmax_lds[t*65 + 32 + c];
            }
        }
    }
    __syncthreads();

    // ---- coalesced output: 512 contiguous floats per block ----
    const size_t ob = (size_t)blockIdx.x * 512;
    #pragma unroll
    for (int j = 0; j < 8; ++j)
        out[ob + j*64 + lane] = out_lds[j*64 + lane];
}

extern "C" void kernel_launch(void* const* d_in, const int* in_sizes, int n_in,
                              void* d_out, int out_size, void* d_ws, size_t ws_size,
                              hipStream_t stream) {
    const float* g_rgb   = (const float*)d_in[0];
    const float* g_nr    = (const float*)d_in[1];
    const float* g_rd    = (const float*)d_in[2];
    const float* g_mask  = (const float*)d_in[3];
    // d_in[4] que_pts, d_in[5] que_dir: unused by the reference
    const float* rd_w1   = (const float*)d_in[6];
    const float* rd_b1   = (const float*)d_in[7];
    const float* rd_w2   = (const float*)d_in[8];
    const float* rd_b2   = (const float*)d_in[9];
    const float* rf_w1   = (const float*)d_in[10];
    const float* rf_b1   = (const float*)d_in[11];
    const float* rf_w2   = (const float*)d_in[12];
    const float* rf_b2   = (const float*)d_in[13];
    const float* nr_w1   = (const float*)d_in[14];
    const float* nr_b1   = (const float*)d_in[15];
    const float* nr_w2   = (const float*)d_in[16];
    const float* nr_b2   = (const float*)d_in[17];
    const float* base_w1 = (const float*)d_in[18];
    const float* base_b1 = (const float*)d_in[19];
    const float* base_w2 = (const float*)d_in[20];
    const float* base_b2 = (const float*)d_in[21];
    const float* vis_w1  = (const float*)d_in[22];
    const float* vis_b1  = (const float*)d_in[23];
    const float* vis_w2  = (const float*)d_in[24];
    const float* vis_b2  = (const float*)d_in[25];
    const float* v2_w1   = (const float*)d_in[26];
    const float* v2_b1   = (const float*)d_in[27];
    const float* v2_w2   = (const float*)d_in[28];
    const float* v2_b2   = (const float*)d_in[29];
    float* out = (float*)d_out;

    hipLaunchKernelGGL(nerf_main, dim3(NRS / 8), dim3(64), 0, stream,
        g_rgb, g_nr, g_rd, g_mask,
        rd_w1, rd_b1, rd_w2, rd_b2,
        rf_w1, rf_b1, rf_w2, rf_b2,
        nr_w1, nr_b1, nr_w2, nr_b2,
        base_w1, base_b1, base_w2, base_b2,
        vis_w1, vis_b1, vis_w2, vis_b2,
        v2_w1, v2_b1, v2_w2, v2_b2,
        out);
}